// Round 4
// baseline (1787.747 us; speedup 1.0000x reference)
//
#include <hip/hip_runtime.h>
#include <stdint.h>

typedef unsigned long long u64;
typedef unsigned int u32;
typedef unsigned char u8;

#define Bn 4
#define Nv 8192
#define Fd 64
#define Ed 65536
#define Kv 4096
#define TGTK 4096   // N - K kills allowed
#define NW 256      // alive bitmap words per batch (8192 bits)
#define SC 8192     // bitonic LDS chunk

// LDS bank-conflict swizzle: bijective (XORs bits[3:6] into bits[0:3]).
#define SWZ8(i) ((i) ^ (((i) >> 3) & 15))

// ---------------- workspace layout (bytes) ----------------
#define WS_FLAGS   ((size_t)0)                         // 1 u32 presence bits
#define WS_ACCCNT  ((size_t)256)                       // Bn u32
#define WS_OUTBITS ((size_t)512)                       // Bn*Kv*128 u32 = 8 MB
#define OUTBITS_BYTES ((size_t)Bn*Kv*128*4)
#define WS_ZERO_BYTES (WS_OUTBITS + OUTBITS_BYTES)     // memset range
#define WS_KEYS    (WS_ZERO_BYTES)                     // Bn*Ed u64 (8-aligned)
#define WS_SQ      (WS_KEYS + (size_t)Bn*Ed*8)         // Bn*Nv f32
#define WS_BND     (WS_SQ + (size_t)Bn*Nv*4)           // Bn*Nv u8
#define WS_MAP     (WS_BND + (size_t)Bn*Nv)            // Bn*Nv i32
#define WS_POS     (WS_MAP + (size_t)Bn*Nv*4)          // Bn*Nv i32
#define WS_PM      (WS_POS + (size_t)Bn*Nv*4)          // Bn*Nv i32
#define WS_ALIST   (WS_PM + (size_t)Bn*Nv*4)           // Bn*Kv i32
#define WS_ACC     (WS_ALIST + (size_t)Bn*Kv*4)        // Bn*TGTK*2 i32
#define WS_PACK    (WS_ACC + (size_t)Bn*TGTK*2*4)      // Bn*Ed u32
#define WS_SPACK   (WS_PACK + (size_t)Bn*Ed*4)         // Bn*Ed u32

// ---------------- per-vertex (+ adj format detection in blocks 0..63) ----------------
__global__ void k_vertex(const float* image, const float* vs, float* sq, u8* bnd, int* map,
                         const u8* adj, u32* flags) {
#pragma clang fp contract(off)
    int idx = blockIdx.x * 256 + threadIdx.x; // b*Nv + v  (grid = Bn*Nv/256 = 128)
    if (blockIdx.x < 64) { // detect: sample first 2 MB of adj (16384 threads, 32 iters)
        const u32* w = (const u32*)adj;
        bool f0 = false, f1 = false, f2 = false, f3 = false;
        for (int i = idx; i < (1 << 19); i += 16384) {
            u32 v = w[i];
            f0 |= (v & 0x000000FFu) != 0;
            f1 |= (v & 0x0000FF00u) != 0;
            f2 |= (v & 0x00FF0000u) != 0;
            f3 |= (v & 0xFF000000u) != 0;
        }
        u32 m = 0;
        if (__ballot(f0)) m |= 1;
        if (__ballot(f1)) m |= 2;
        if (__ballot(f2)) m |= 4;
        if (__ballot(f3)) m |= 8;
        if ((threadIdx.x & 63) == 0 && m) atomicOr(flags, m);
    }
    if (idx >= Bn * Nv) return;
    const float* row = image + (size_t)idx * Fd;
    float r[8];
#pragma unroll
    for (int j = 0; j < 8; ++j) r[j] = row[j] * row[j];
#pragma unroll
    for (int i = 8; i < 64; i += 8)
#pragma unroll
        for (int j = 0; j < 8; ++j) r[j] += row[i + j] * row[i + j];
    float s = ((r[0] + r[1]) + (r[2] + r[3])) + ((r[4] + r[5]) + (r[6] + r[7]));
    sq[idx] = s;
    float x = vs[(size_t)idx * 2], y = vs[(size_t)idx * 2 + 1];
    const float LO = 0.05f;
    const float HI = (float)(1.0 - 0.05);
    bnd[idx] = ((x < LO) || (x > HI) || (y < LO) || (y > HI)) ? 1 : 0;
    map[idx] = idx & (Nv - 1);
}

// ---------------- per-edge: key (non-ok edges get +inf key -> sort to tail; no atomics) ----------------
__global__ void k_edge(const int* edges, const float* sq, const u8* bnd, u64* keys, u32* pack) {
    int idx = blockIdx.x * 256 + threadIdx.x; // b*Ed + e
    if (idx >= Bn * Ed) return;
    int b = idx >> 16, e = idx & (Ed - 1);
    int v0 = edges[(size_t)b * 2 * Ed + e];
    int v1 = edges[(size_t)b * 2 * Ed + Ed + e];
    float c = sq[b * Nv + v0] + sq[b * Nv + v1];
    u32 okk = (!bnd[b * Nv + v0] && !bnd[b * Nv + v1]) ? 1u : 0u;
    pack[idx] = (u32)v0 | ((u32)v1 << 13) | (okk << 26);
    keys[idx] = okk ? (((u64)__float_as_uint(c) << 16) | (u32)e) : ~0ull;
}

// ---------------- bitonic sort (per-batch arrays of 65536 u64) ----------------
__device__ __forceinline__ void bitonic_cas(u64* s, int i, int pa, bool asc) {
    u64 a = s[i], c = s[pa];
    if ((a > c) == asc) { s[i] = c; s[pa] = a; }
}
__device__ __forceinline__ void cex(u64& a, u64& b, bool asc) {
    if ((a > b) == asc) { u64 t = a; a = b; b = t; }
}

// local sort chunks of SC; j<=4 stages in registers (thread owns 8 contiguous elems)
__global__ __launch_bounds__(1024) void k_sortA(u64* keys) {
    __shared__ u64 s[SC];
    int b = blockIdx.x >> 3, ch = blockIdx.x & 7;
    u64* base = keys + (size_t)b * Ed + (size_t)ch * SC;
    int gb = ch * SC;
    int t8 = threadIdx.x * 8;
    u64 r[8];
#pragma unroll
    for (int u = 0; u < 8; ++u) r[u] = base[t8 + u];
    cex(r[0], r[1], true); cex(r[2], r[3], false); cex(r[4], r[5], true); cex(r[6], r[7], false);
    cex(r[0], r[2], true); cex(r[1], r[3], true); cex(r[4], r[6], false); cex(r[5], r[7], false);
    cex(r[0], r[1], true); cex(r[2], r[3], true); cex(r[4], r[5], false); cex(r[6], r[7], false);
    {
        bool a8 = (((gb + t8) & 8) == 0);
        cex(r[0], r[4], a8); cex(r[1], r[5], a8); cex(r[2], r[6], a8); cex(r[3], r[7], a8);
        cex(r[0], r[2], a8); cex(r[1], r[3], a8); cex(r[4], r[6], a8); cex(r[5], r[7], a8);
        cex(r[0], r[1], a8); cex(r[2], r[3], a8); cex(r[4], r[5], a8); cex(r[6], r[7], a8);
    }
#pragma unroll
    for (int u = 0; u < 8; ++u) s[SWZ8(t8 + u)] = r[u];
    __syncthreads();
    for (int k = 16; k <= SC; k <<= 1) {
        for (int j = k >> 1; j >= 8; j >>= 1) {
#pragma unroll
            for (int p = 0; p < SC / 2048; ++p) {
                int t = p * 1024 + threadIdx.x;
                int i = ((t & ~(j - 1)) << 1) | (t & (j - 1));
                bool asc = (((gb + i) & k) == 0);
                bitonic_cas(s, SWZ8(i), SWZ8(i | j), asc);
            }
            __syncthreads();
        }
        bool asc = (((gb + t8) & k) == 0);
#pragma unroll
        for (int u = 0; u < 8; ++u) r[u] = s[SWZ8(t8 + u)];
        cex(r[0], r[4], asc); cex(r[1], r[5], asc); cex(r[2], r[6], asc); cex(r[3], r[7], asc);
        cex(r[0], r[2], asc); cex(r[1], r[3], asc); cex(r[4], r[6], asc); cex(r[5], r[7], asc);
        cex(r[0], r[1], asc); cex(r[2], r[3], asc); cex(r[4], r[5], asc); cex(r[6], r[7], asc);
        if (k == SC) {
#pragma unroll
            for (int u = 0; u < 8; ++u) base[t8 + u] = r[u];
        } else {
#pragma unroll
            for (int u = 0; u < 8; ++u) s[SWZ8(t8 + u)] = r[u];
            __syncthreads();
        }
    }
}

// fused merge level: vertical stages (j>=8192) computed redundantly per chunk
// (per column, a 1/2/3-stage bitonic network over chunk values; identical CAS
// sequence/directions to the old k_sortV), keep own chunk's value, then the
// LDS passes j<=4096 and register finish. Final level (dofin) emits spack.
__global__ __launch_bounds__(1024) void k_sortVC(u64* keys, int k,
                                                 const u32* pack, u32* spack, int dofin) {
    __shared__ u64 s[SC];
    int b = blockIdx.x >> 3, ch = blockIdx.x & 7;
    const size_t bofs = (size_t)b * Ed;
    int gb = ch * SC;
    if (k == 65536) {            // 3 vertical stages, asc everywhere
        for (int p = 0; p < 8; ++p) {
            int c = p * 1024 + threadIdx.x;
            u64 v[8];
#pragma unroll
            for (int m = 0; m < 8; ++m) v[m] = keys[bofs + (size_t)m * SC + c];
            cex(v[0], v[4], true); cex(v[1], v[5], true); cex(v[2], v[6], true); cex(v[3], v[7], true);
            cex(v[0], v[2], true); cex(v[1], v[3], true); cex(v[4], v[6], true); cex(v[5], v[7], true);
            cex(v[0], v[1], true); cex(v[2], v[3], true); cex(v[4], v[5], true); cex(v[6], v[7], true);
            s[SWZ8(c)] = v[ch];
        }
    } else if (k == 32768) {     // 2 stages within chunk group of 4; asc = (ch<4)
        int g4 = ch & 4;
        bool adir = (ch < 4);
        for (int p = 0; p < 8; ++p) {
            int c = p * 1024 + threadIdx.x;
            u64 v[4];
#pragma unroll
            for (int m = 0; m < 4; ++m) v[m] = keys[bofs + (size_t)(g4 + m) * SC + c];
            cex(v[0], v[2], adir); cex(v[1], v[3], adir);
            cex(v[0], v[1], adir); cex(v[2], v[3], adir);
            s[SWZ8(c)] = v[ch & 3];
        }
    } else {                     // k == 16384: 1 stage within chunk pair; asc = ((ch&2)==0)
        int g2 = ch & 6;
        bool adir = ((ch & 2) == 0);
        for (int p = 0; p < 8; ++p) {
            int c = p * 1024 + threadIdx.x;
            u64 v0 = keys[bofs + (size_t)g2 * SC + c];
            u64 v1 = keys[bofs + (size_t)(g2 + 1) * SC + c];
            cex(v0, v1, adir);
            s[SWZ8(c)] = (ch & 1) ? v1 : v0;
        }
    }
    __syncthreads();
    bool asc = ((gb & k) == 0);
    for (int j = SC / 2; j >= 8; j >>= 1) {
#pragma unroll
        for (int p = 0; p < SC / 2048; ++p) {
            int t = p * 1024 + threadIdx.x;
            int i = ((t & ~(j - 1)) << 1) | (t & (j - 1));
            bitonic_cas(s, SWZ8(i), SWZ8(i | j), asc);
        }
        __syncthreads();
    }
    int t8 = threadIdx.x * 8;
    u64 r[8];
#pragma unroll
    for (int u = 0; u < 8; ++u) r[u] = s[SWZ8(t8 + u)];
    cex(r[0], r[4], asc); cex(r[1], r[5], asc); cex(r[2], r[6], asc); cex(r[3], r[7], asc);
    cex(r[0], r[2], asc); cex(r[1], r[3], asc); cex(r[4], r[6], asc); cex(r[5], r[7], asc);
    cex(r[0], r[1], asc); cex(r[2], r[3], asc); cex(r[4], r[5], asc); cex(r[6], r[7], asc);
    if (dofin) {
        const u32* pk = pack + bofs;
        u32* sp = spack + bofs + (size_t)ch * SC;
#pragma unroll
        for (int u = 0; u < 8; ++u)
            sp[t8 + u] = (r[u] == ~0ull) ? 0u : pk[(u32)(r[u] & 0xFFFFu)];
    } else {
        u64* base = keys + bofs + (size_t)ch * SC;
#pragma unroll
        for (int u = 0; u < 8; ++u) base[t8 + u] = r[u];
    }
}

// ---------------- greedy collapse + fused alive-rank scan: 1 wave per batch ----------------
__global__ __launch_bounds__(64) void k_greedy(const u32* spack, int* map,
                                               int* accList, u32* accCnt,
                                               int* pos, int* pm, int* alist) {
    int b = blockIdx.x;
    int lane = threadIdx.x;
    __shared__ u32 alive[NW];
    __shared__ u32 mlane[Nv]; // registry during loop; reused as pos[] after
    for (int i = lane; i < NW; i += 64) alive[i] = 0xFFFFFFFFu;
    for (int i = lane; i < Nv; i += 64) mlane[i] = 0x7FFFFFFFu;
    const u32* sp = spack + (size_t)b * Ed;
    u32 pa = sp[lane], pb = sp[64 + lane]; // prefetch group 0
    __syncthreads();
    int nk = 0;
    const int G = Ed / 128;
    for (int g = 0; g < G; ++g) {
        u32 na = 0u, nb = 0u;
        if (g + 1 < G) { na = sp[(g + 1) * 128 + lane]; nb = sp[(g + 1) * 128 + 64 + lane]; }
        int v0a = pa & 8191, v1a = (pa >> 13) & 8191; bool oka = (pa >> 26) & 1u;
        int v0b = pb & 8191, v1b = (pb >> 13) & 8191; bool okb = (pb >> 26) & 1u;
        u32 gi = (u32)(G + 1 - g) << 8; // strictly decreasing generation base
        if (oka) atomicMin(&mlane[v1a], gi | (u32)lane);
        if (okb) atomicMin(&mlane[v1b], gi | (u32)(64 + lane));
        __syncthreads(); // drains registrations AND previous group's kill-writes
        u32 aw0a = alive[v0a >> 5], aw1a = alive[v1a >> 5];
        u32 aw0b = alive[v0b >> 5], aw1b = alive[v1b >> 5];
        u32 m0a = mlane[v0a], m1a = mlane[v1a];
        u32 m0b = mlane[v0b], m1b = mlane[v1b];
        bool specA = oka && ((aw0a >> (v0a & 31)) & 1u) && ((aw1a >> (v1a & 31)) & 1u);
        bool specB = okb && ((aw0b >> (v0b & 31)) & 1u) && ((aw1b >> (v1b & 31)) & 1u);
        u32 slA = (u32)lane, slB = (u32)(64 + lane);
        bool confA = specA && ((((m0a & 0xFFFFFF00u) == gi) && ((m0a & 255u) < slA)) ||
                               (((m1a & 0xFFFFFF00u) == gi) && ((m1a & 255u) < slA)));
        bool confB = specB && ((((m0b & 0xFFFFFF00u) == gi) && ((m0b & 255u) < slB)) ||
                               (((m1b & 0xFFFFFF00u) == gi) && ((m1b & 255u) < slB)));
        u64 specLo = __ballot(specA), specHi = __ballot(specB);
        u64 confLo = __ballot(confA), confHi = __ballot(confB);
        u64 accLo = specLo & ~confLo, accHi = specHi & ~confHi;
        u64 rem = confLo; // resolve conflicted slots in slot order (lo then hi)
        while (rem) {
            int l = __ffsll((unsigned long long)rem) - 1; rem &= rem - 1;
            int bv0 = __shfl(v0a, l), bv1 = __shfl(v1a, l);
            bool kA = ((accLo >> lane) & 1ull) && (lane < l) && (v1a == bv0 || v1a == bv1);
            if (__ballot(kA) == 0ull) accLo |= 1ull << l;
        }
        rem = confHi;
        while (rem) {
            int l = __ffsll((unsigned long long)rem) - 1; rem &= rem - 1;
            int bv0 = __shfl(v0b, l), bv1 = __shfl(v1b, l);
            bool kA = ((accLo >> lane) & 1ull) && (v1a == bv0 || v1a == bv1); // lo slots all earlier
            bool kB = ((accHi >> lane) & 1ull) && (lane < l) && (v1b == bv0 || v1b == bv1);
            if ((__ballot(kA) | __ballot(kB)) == 0ull) accHi |= 1ull << l;
        }
        int cntLo = __popcll(accLo);
        int cnt = cntLo + __popcll(accHi);
        int remK = TGTK - nk;
        bool accA = (accLo >> lane) & 1ull;
        bool accB = (accHi >> lane) & 1ull;
        if (cnt > remK) { // keep first remK accepts in slot order (pre-trim ranks)
            int rA = __popcll(accLo & ((1ull << lane) - 1ull));
            if (accA && rA >= remK) accA = false;
            int rB = cntLo + __popcll(accHi & ((1ull << lane) - 1ull));
            if (accB && rB >= remK) accB = false;
            accLo = __ballot(accA); accHi = __ballot(accB);
            cntLo = __popcll(accLo);
            cnt = remK;
        }
        if (accA) {
            atomicAnd(&alive[v1a >> 5], ~(1u << (v1a & 31)));
            map[(size_t)b * Nv + v1a] = v0a;
            int r = __popcll(accLo & ((1ull << lane) - 1ull));
            int slot = nk + r;
            accList[((size_t)b * TGTK + slot) * 2] = v0a;
            accList[((size_t)b * TGTK + slot) * 2 + 1] = v1a;
        }
        if (accB) {
            atomicAnd(&alive[v1b >> 5], ~(1u << (v1b & 31)));
            map[(size_t)b * Nv + v1b] = v0b;
            int r = cntLo + __popcll(accHi & ((1ull << lane) - 1ull));
            int slot = nk + r;
            accList[((size_t)b * TGTK + slot) * 2] = v0b;
            accList[((size_t)b * TGTK + slot) * 2 + 1] = v1b;
        }
        nk += cnt;
        if (nk >= TGTK) break;
        pa = na; pb = nb;
    }
    if (lane == 0) accCnt[b] = (u32)nk;
    // ---------------- fused scan: ranks of alive vertices ----------------
    __syncthreads();
    __threadfence(); // commit this wave's map[] kill-writes before re-reading below
    u32 w0 = alive[lane * 4], w1 = alive[lane * 4 + 1];
    u32 w2 = alive[lane * 4 + 2], w3 = alive[lane * 4 + 3];
    u32 c0 = __popc(w0), c1 = __popc(w1), c2 = __popc(w2), c3 = __popc(w3);
    u32 lsum = c0 + c1 + c2 + c3;
    u32 incl = lsum;
#pragma unroll
    for (int d = 1; d < 64; d <<= 1) { u32 t = __shfl_up(incl, d); if (lane >= d) incl += t; }
    u32 base = incl - lsum; // exclusive prefix: rank base for vertex 128*lane
    int* posb = pos + (size_t)b * Nv;
    int* alb = alist + (size_t)b * Kv;
    __syncthreads(); // registry reads done; reuse mlane as pos[]
    u32 wv[4] = { w0, w1, w2, w3 };
    for (int q = 0; q < 4; ++q) {
        u32 w = wv[q];
        int vb = lane * 128 + q * 32;
        for (int bit = 0; bit < 32; ++bit) {
            int v = vb + bit;
            int p = -1;
            if ((w >> bit) & 1u) {
                if (base < Kv) { p = (int)base; alb[base] = v; }
                base++;
            }
            mlane[v] = (u32)p;
            posb[v] = p;
        }
    }
    __syncthreads();
    const int* mapb = map + (size_t)b * Nv;
    int* pmb = pm + (size_t)b * Nv;
    for (int v = lane; v < Nv; v += 64) pmb[v] = (int)mlane[(u32)mapb[v]];
}

// ---------------- features: copy surviving rows, then scatter-add absorbed rows ----------------
__global__ void k_fcopy(const float* image, const int* alist, float* outF) {
    int idx = blockIdx.x * 256 + threadIdx.x; // Bn*Kv*16
    if (idx >= Bn * Kv * 16) return;
    int b = idx >> 16, r = idx & 65535;
    int x = r >> 4, f4 = r & 15;
    int src = alist[b * Kv + x];
    const float4* s = (const float4*)(image + ((size_t)(b * Nv + src)) * Fd) + f4;
    float4* d = (float4*)(outF + ((size_t)(b * Kv + x)) * Fd) + f4;
    *d = *s;
}

__global__ __launch_bounds__(64) void k_fscat(const float* image, const int* accList,
                                              const u32* accCnt, const int* pos, float* outF) {
    int b = blockIdx.x >> 12, e = blockIdx.x & 4095;
    if (e >= (int)accCnt[b]) return;
    int v0 = accList[((size_t)b * TGTK + e) * 2];
    int v1 = accList[((size_t)b * TGTK + e) * 2 + 1];
    int x = pos[(size_t)b * Nv + v0];
    if (x < 0) return;
    int f = threadIdx.x;
    atomicAdd(outF + ((size_t)(b * Kv + x)) * Fd + f,
              image[((size_t)(b * Nv + v1)) * Fd + f]);
}

// ---------------- adjacency: merge rows/cols into K-bit bitsets ----------------
__global__ __launch_bounds__(256) void k_merge(const u8* adj, const u32* flags,
                                               const int* pm, u32* outbits) {
    int bi = blockIdx.x; // Bn*Nv
    int b = bi >> 13, i = bi & (Nv - 1);
    int t = pm[(size_t)b * Nv + i];
    if (t < 0) return;
    __shared__ u32 bits[Kv / 32]; // 128 words
    int tid = threadIdx.x;
    if (tid < 128) bits[tid] = 0;
    __syncthreads();
    const int* pmb = pm + (size_t)b * Nv;
    u32 fw = flags[0];
    bool bytefmt = (fw & 1) && (fw & 8);
    auto put = [&](int col) {
        int c = pmb[col];
        if (c >= 0) atomicOr(&bits[c >> 5], 1u << (c & 31));
    };
    if (bytefmt) {
        const uint4* row = (const uint4*)(adj + ((size_t)b * Nv + i) * Nv);
#pragma unroll
        for (int it = 0; it < 2; ++it) {
            uint4 v = row[it * 256 + tid];
            if (v.x | v.y | v.z | v.w) {
                int cb = (it * 256 + tid) * 16;
                u32 wv[4] = { v.x, v.y, v.z, v.w };
                for (int q = 0; q < 4; ++q) {
                    u32 u = wv[q];
                    if (!u) continue;
#pragma unroll
                    for (int kk = 0; kk < 4; ++kk)
                        if ((u >> (8 * kk)) & 0xFFu) put(cb + q * 4 + kk);
                }
            }
        }
    } else {
        const uint4* row = (const uint4*)((const u32*)adj + ((size_t)b * Nv + i) * Nv);
        for (int it = 0; it < 8; ++it) {
            uint4 v = row[it * 256 + tid];
            int cb = (it * 256 + tid) * 4;
            if (v.x) put(cb);
            if (v.y) put(cb + 1);
            if (v.z) put(cb + 2);
            if (v.w) put(cb + 3);
        }
    }
    __syncthreads();
    if (tid < 128) {
        u32 bw = bits[tid];
        if (bw) atomicOr(&outbits[((size_t)b * Kv + t) * 128 + tid], bw);
    }
}

// ---------------- expand bitsets to float adjacency, zero diagonal ----------------
__global__ void k_expand(const u32* outbits, float* out) {
    int idx = blockIdx.x; // Bn*Kv*4
    int tid = threadIdx.x;
    int b = idx >> 14, r = idx & 16383;
    int x = r >> 2, seg = r & 3;
    int c0 = seg * 1024 + tid * 4;
    u32 w = outbits[((size_t)b * Kv + x) * 128 + (c0 >> 5)];
    u32 nib = (w >> (c0 & 31)) & 0xFu;
    float4 f;
    f.x = (nib & 1) ? 1.f : 0.f;
    f.y = (nib & 2) ? 1.f : 0.f;
    f.z = (nib & 4) ? 1.f : 0.f;
    f.w = (nib & 8) ? 1.f : 0.f;
    if (x >= c0 && x < c0 + 4) ((float*)&f)[x - c0] = 0.f;
    *((float4*)(out + ((size_t)(b * Kv + x)) * Kv + c0)) = f;
}

extern "C" void kernel_launch(void* const* d_in, const int* in_sizes, int n_in,
                              void* d_out, int out_size, void* d_ws, size_t ws_size,
                              hipStream_t stream) {
    const u8* adj = (const u8*)d_in[0];
    const float* image = (const float*)d_in[1];
    const float* vs = (const float*)d_in[2];
    const int* edges = (const int*)d_in[3];
    char* ws = (char*)d_ws;
    u32* flags = (u32*)(ws + WS_FLAGS);
    u32* accCnt = (u32*)(ws + WS_ACCCNT);
    u32* outbits = (u32*)(ws + WS_OUTBITS);
    u64* keys = (u64*)(ws + WS_KEYS);
    float* sq = (float*)(ws + WS_SQ);
    u8* bnd = (u8*)(ws + WS_BND);
    int* map = (int*)(ws + WS_MAP);
    int* pos = (int*)(ws + WS_POS);
    int* pm = (int*)(ws + WS_PM);
    int* alist = (int*)(ws + WS_ALIST);
    int* accList = (int*)(ws + WS_ACC);
    u32* pack = (u32*)(ws + WS_PACK);
    u32* spack = (u32*)(ws + WS_SPACK);
    float* outA = (float*)d_out;
    float* outF = outA + (size_t)Bn * Kv * Kv;

    hipMemsetAsync(d_ws, 0, WS_ZERO_BYTES, stream);
    k_vertex<<<Bn * Nv / 256, 256, 0, stream>>>(image, vs, sq, bnd, map, adj, flags);
    k_edge<<<Bn * Ed / 256, 256, 0, stream>>>(edges, sq, bnd, keys, pack);
    // bitonic sort: local chunks, then fused vertical+LDS merge levels
    k_sortA<<<Bn * 8, 1024, 0, stream>>>(keys);
    k_sortVC<<<Bn * 8, 1024, 0, stream>>>(keys, 16384, pack, spack, 0);
    k_sortVC<<<Bn * 8, 1024, 0, stream>>>(keys, 32768, pack, spack, 0);
    k_sortVC<<<Bn * 8, 1024, 0, stream>>>(keys, 65536, pack, spack, 1);
    k_greedy<<<Bn, 64, 0, stream>>>(spack, map, accList, accCnt, pos, pm, alist);
    k_fcopy<<<Bn * Kv * 16 / 256, 256, 0, stream>>>(image, alist, outF);
    k_fscat<<<Bn * TGTK, 64, 0, stream>>>(image, accList, accCnt, pos, outF);
    k_merge<<<Bn * Nv, 256, 0, stream>>>(adj, flags, pm, outbits);
    k_expand<<<Bn * Kv * 4, 256, 0, stream>>>(outbits, outA);
}

// Round 5
// 1760.073 us; speedup vs baseline: 1.0157x; 1.0157x over previous
//
#include <hip/hip_runtime.h>
#include <stdint.h>

typedef unsigned long long u64;
typedef unsigned int u32;
typedef unsigned char u8;

#define Bn 4
#define Nv 8192
#define Fd 64
#define Ed 65536
#define Kv 4096
#define TGTK 4096   // N - K kills allowed
#define NW 256      // alive bitmap words per batch (8192 bits)
#define SC 8192     // bitonic LDS chunk

// LDS bank-conflict swizzle: bijective (XORs bits[3:6] into bits[0:3]).
#define SWZ8(i) ((i) ^ (((i) >> 3) & 15))

// ---------------- workspace layout (bytes) ----------------
#define WS_FLAGS   ((size_t)0)                         // 1 u32 presence bits
#define WS_ACCCNT  ((size_t)256)                       // Bn u32
#define WS_ZERO_BYTES ((size_t)512)                    // memset range (flags only)
#define WS_OUTBITS ((size_t)512)                       // Bn*Kv*128 u32 = 8 MB (zeroed in k_fcopy)
#define OUTBITS_BYTES ((size_t)Bn*Kv*128*4)
#define WS_KEYS    (WS_OUTBITS + OUTBITS_BYTES)        // Bn*Ed u64 (8-aligned)
#define WS_SQ      (WS_KEYS + (size_t)Bn*Ed*8)         // Bn*Nv f32
#define WS_BND     (WS_SQ + (size_t)Bn*Nv*4)           // Bn*Nv u8
#define WS_MAP     (WS_BND + (size_t)Bn*Nv)            // Bn*Nv i32
#define WS_POS     (WS_MAP + (size_t)Bn*Nv*4)          // Bn*Nv i32
#define WS_PM      (WS_POS + (size_t)Bn*Nv*4)          // Bn*Nv i32
#define WS_ALIST   (WS_PM + (size_t)Bn*Nv*4)           // Bn*Kv i32
#define WS_ACC     (WS_ALIST + (size_t)Bn*Kv*4)        // Bn*TGTK*2 i32
#define WS_PACK    (WS_ACC + (size_t)Bn*TGTK*2*4)      // Bn*Ed u32
#define WS_SPACK   (WS_PACK + (size_t)Bn*Ed*4)         // Bn*Ed u32

// ---------------- per-vertex (+ adj format detection in blocks 0..63) ----------------
__global__ void k_vertex(const float* image, const float* vs, float* sq, u8* bnd, int* map,
                         const u8* adj, u32* flags) {
#pragma clang fp contract(off)
    int idx = blockIdx.x * 256 + threadIdx.x; // b*Nv + v  (grid = Bn*Nv/256 = 128)
    if (blockIdx.x < 64) { // detect: sample first 2 MB of adj (16384 threads, 32 iters)
        const u32* w = (const u32*)adj;
        bool f0 = false, f1 = false, f2 = false, f3 = false;
        for (int i = idx; i < (1 << 19); i += 16384) {
            u32 v = w[i];
            f0 |= (v & 0x000000FFu) != 0;
            f1 |= (v & 0x0000FF00u) != 0;
            f2 |= (v & 0x00FF0000u) != 0;
            f3 |= (v & 0xFF000000u) != 0;
        }
        u32 m = 0;
        if (__ballot(f0)) m |= 1;
        if (__ballot(f1)) m |= 2;
        if (__ballot(f2)) m |= 4;
        if (__ballot(f3)) m |= 8;
        if ((threadIdx.x & 63) == 0 && m) atomicOr(flags, m);
    }
    if (idx >= Bn * Nv) return;
    const float* row = image + (size_t)idx * Fd;
    float r[8];
#pragma unroll
    for (int j = 0; j < 8; ++j) r[j] = row[j] * row[j];
#pragma unroll
    for (int i = 8; i < 64; i += 8)
#pragma unroll
        for (int j = 0; j < 8; ++j) r[j] += row[i + j] * row[i + j];
    float s = ((r[0] + r[1]) + (r[2] + r[3])) + ((r[4] + r[5]) + (r[6] + r[7]));
    sq[idx] = s;
    float x = vs[(size_t)idx * 2], y = vs[(size_t)idx * 2 + 1];
    const float LO = 0.05f;
    const float HI = (float)(1.0 - 0.05);
    bnd[idx] = ((x < LO) || (x > HI) || (y < LO) || (y > HI)) ? 1 : 0;
    map[idx] = idx & (Nv - 1);
}

// ---------------- per-edge: key (non-ok edges get +inf key -> sort to tail; no atomics) ----------------
__global__ void k_edge(const int* edges, const float* sq, const u8* bnd, u64* keys, u32* pack) {
    int idx = blockIdx.x * 256 + threadIdx.x; // b*Ed + e
    if (idx >= Bn * Ed) return;
    int b = idx >> 16, e = idx & (Ed - 1);
    int v0 = edges[(size_t)b * 2 * Ed + e];
    int v1 = edges[(size_t)b * 2 * Ed + Ed + e];
    float c = sq[b * Nv + v0] + sq[b * Nv + v1];
    u32 okk = (!bnd[b * Nv + v0] && !bnd[b * Nv + v1]) ? 1u : 0u;
    pack[idx] = (u32)v0 | ((u32)v1 << 13) | (okk << 26);
    keys[idx] = okk ? (((u64)__float_as_uint(c) << 16) | (u32)e) : ~0ull;
}

// ---------------- bitonic sort (per-batch arrays of 65536 u64) ----------------
__device__ __forceinline__ void bitonic_cas(u64* s, int i, int pa, bool asc) {
    u64 a = s[i], c = s[pa];
    if ((a > c) == asc) { s[i] = c; s[pa] = a; }
}
__device__ __forceinline__ void cex(u64& a, u64& b, bool asc) {
    if ((a > b) == asc) { u64 t = a; a = b; b = t; }
}

// local sort chunks of SC; j<=4 stages in registers (thread owns 8 contiguous elems)
__global__ __launch_bounds__(1024) void k_sortA(u64* keys) {
    __shared__ u64 s[SC];
    int b = blockIdx.x >> 3, ch = blockIdx.x & 7;
    u64* base = keys + (size_t)b * Ed + (size_t)ch * SC;
    int gb = ch * SC;
    int t8 = threadIdx.x * 8;
    u64 r[8];
#pragma unroll
    for (int u = 0; u < 8; ++u) r[u] = base[t8 + u];
    cex(r[0], r[1], true); cex(r[2], r[3], false); cex(r[4], r[5], true); cex(r[6], r[7], false);
    cex(r[0], r[2], true); cex(r[1], r[3], true); cex(r[4], r[6], false); cex(r[5], r[7], false);
    cex(r[0], r[1], true); cex(r[2], r[3], true); cex(r[4], r[5], false); cex(r[6], r[7], false);
    {
        bool a8 = (((gb + t8) & 8) == 0);
        cex(r[0], r[4], a8); cex(r[1], r[5], a8); cex(r[2], r[6], a8); cex(r[3], r[7], a8);
        cex(r[0], r[2], a8); cex(r[1], r[3], a8); cex(r[4], r[6], a8); cex(r[5], r[7], a8);
        cex(r[0], r[1], a8); cex(r[2], r[3], a8); cex(r[4], r[5], a8); cex(r[6], r[7], a8);
    }
#pragma unroll
    for (int u = 0; u < 8; ++u) s[SWZ8(t8 + u)] = r[u];
    __syncthreads();
    for (int k = 16; k <= SC; k <<= 1) {
        for (int j = k >> 1; j >= 8; j >>= 1) {
#pragma unroll
            for (int p = 0; p < SC / 2048; ++p) {
                int t = p * 1024 + threadIdx.x;
                int i = ((t & ~(j - 1)) << 1) | (t & (j - 1));
                bool asc = (((gb + i) & k) == 0);
                bitonic_cas(s, SWZ8(i), SWZ8(i | j), asc);
            }
            __syncthreads();
        }
        bool asc = (((gb + t8) & k) == 0);
#pragma unroll
        for (int u = 0; u < 8; ++u) r[u] = s[SWZ8(t8 + u)];
        cex(r[0], r[4], asc); cex(r[1], r[5], asc); cex(r[2], r[6], asc); cex(r[3], r[7], asc);
        cex(r[0], r[2], asc); cex(r[1], r[3], asc); cex(r[4], r[6], asc); cex(r[5], r[7], asc);
        cex(r[0], r[1], asc); cex(r[2], r[3], asc); cex(r[4], r[5], asc); cex(r[6], r[7], asc);
        if (k == SC) {
#pragma unroll
            for (int u = 0; u < 8; ++u) base[t8 + u] = r[u];
        } else {
#pragma unroll
            for (int u = 0; u < 8; ++u) s[SWZ8(t8 + u)] = r[u];
            __syncthreads();
        }
    }
}

// vertical register passes: all j>=8192 stages of one k-level in a single launch.
// Thread owns column c (stride-8192 set of 8 elems); directions are per-m constants.
__global__ __launch_bounds__(1024) void k_sortV(u64* keys, int k) {
    int b = blockIdx.x >> 3;
    int c = (blockIdx.x & 7) * 1024 + threadIdx.x; // 0..8191
    u64* base = keys + (size_t)b * Ed + c;
    u64 r[8];
#pragma unroll
    for (int m = 0; m < 8; ++m) r[m] = base[(size_t)m * 8192];
    if (k == 65536) { // asc everywhere
        cex(r[0], r[4], true); cex(r[1], r[5], true); cex(r[2], r[6], true); cex(r[3], r[7], true);
        cex(r[0], r[2], true); cex(r[1], r[3], true); cex(r[4], r[6], true); cex(r[5], r[7], true);
        cex(r[0], r[1], true); cex(r[2], r[3], true); cex(r[4], r[5], true); cex(r[6], r[7], true);
    } else if (k == 32768) { // asc = bit15==0
        cex(r[0], r[2], true); cex(r[1], r[3], true); cex(r[4], r[6], false); cex(r[5], r[7], false);
        cex(r[0], r[1], true); cex(r[2], r[3], true); cex(r[4], r[5], false); cex(r[6], r[7], false);
    } else { // k == 16384: asc = bit14==0
        cex(r[0], r[1], true); cex(r[2], r[3], false); cex(r[4], r[5], true); cex(r[6], r[7], false);
    }
#pragma unroll
    for (int m = 0; m < 8; ++m) base[(size_t)m * 8192] = r[m];
}

// finish j<=SC/2 in LDS (k > SC: direction constant per chunk); j<=4 in registers.
// Final pass (dofin): emit spack directly; pad keys (~0) -> spack 0 (okk=0).
__global__ __launch_bounds__(1024) void k_sortC(u64* keys, int k,
                                                const u32* pack, u32* spack, int dofin) {
    __shared__ u64 s[SC];
    int b = blockIdx.x >> 3, ch = blockIdx.x & 7;
    u64* base = keys + (size_t)b * Ed + (size_t)ch * SC;
    int gb = ch * SC;
    for (int p = 0; p < SC / 1024; ++p) {
        int i = p * 1024 + threadIdx.x;
        s[SWZ8(i)] = base[i];
    }
    __syncthreads();
    bool asc = ((gb & k) == 0);
    for (int j = SC / 2; j >= 8; j >>= 1) {
#pragma unroll
        for (int p = 0; p < SC / 2048; ++p) {
            int t = p * 1024 + threadIdx.x;
            int i = ((t & ~(j - 1)) << 1) | (t & (j - 1));
            bitonic_cas(s, SWZ8(i), SWZ8(i | j), asc);
        }
        __syncthreads();
    }
    int t8 = threadIdx.x * 8;
    u64 r[8];
#pragma unroll
    for (int u = 0; u < 8; ++u) r[u] = s[SWZ8(t8 + u)];
    cex(r[0], r[4], asc); cex(r[1], r[5], asc); cex(r[2], r[6], asc); cex(r[3], r[7], asc);
    cex(r[0], r[2], asc); cex(r[1], r[3], asc); cex(r[4], r[6], asc); cex(r[5], r[7], asc);
    cex(r[0], r[1], asc); cex(r[2], r[3], asc); cex(r[4], r[5], asc); cex(r[6], r[7], asc);
    if (dofin) {
        const u32* pk = pack + (size_t)b * Ed;
        u32* sp = spack + (size_t)b * Ed + (size_t)ch * SC;
#pragma unroll
        for (int u = 0; u < 8; ++u)
            sp[t8 + u] = (r[u] == ~0ull) ? 0u : pk[(u32)(r[u] & 0xFFFFu)];
    } else {
#pragma unroll
        for (int u = 0; u < 8; ++u) base[t8 + u] = r[u];
    }
}

// ---------------- greedy collapse + fused alive-rank scan: 1 wave per batch ----------------
__global__ __launch_bounds__(64) void k_greedy(const u32* spack, int* map,
                                               int* accList, u32* accCnt,
                                               int* pos, int* pm, int* alist) {
    int b = blockIdx.x;
    int lane = threadIdx.x;
    __shared__ u32 alive[NW];
    __shared__ u32 mlane[Nv]; // registry during loop; reused as pos[] after
    for (int i = lane; i < NW; i += 64) alive[i] = 0xFFFFFFFFu;
    for (int i = lane; i < Nv; i += 64) mlane[i] = 0x7FFFFFFFu;
    const u32* sp = spack + (size_t)b * Ed;
    u32 pa = sp[lane], pb = sp[64 + lane]; // prefetch group 0
    __syncthreads();
    int nk = 0;
    const int G = Ed / 128;
    for (int g = 0; g < G; ++g) {
        u32 na = 0u, nb = 0u;
        if (g + 1 < G) { na = sp[(g + 1) * 128 + lane]; nb = sp[(g + 1) * 128 + 64 + lane]; }
        int v0a = pa & 8191, v1a = (pa >> 13) & 8191; bool oka = (pa >> 26) & 1u;
        int v0b = pb & 8191, v1b = (pb >> 13) & 8191; bool okb = (pb >> 26) & 1u;
        u32 gi = (u32)(G + 1 - g) << 8; // strictly decreasing generation base
        if (oka) atomicMin(&mlane[v1a], gi | (u32)lane);
        if (okb) atomicMin(&mlane[v1b], gi | (u32)(64 + lane));
        __syncthreads(); // drains registrations AND previous group's kill-writes
        u32 aw0a = alive[v0a >> 5], aw1a = alive[v1a >> 5];
        u32 aw0b = alive[v0b >> 5], aw1b = alive[v1b >> 5];
        u32 m0a = mlane[v0a], m1a = mlane[v1a];
        u32 m0b = mlane[v0b], m1b = mlane[v1b];
        bool specA = oka && ((aw0a >> (v0a & 31)) & 1u) && ((aw1a >> (v1a & 31)) & 1u);
        bool specB = okb && ((aw0b >> (v0b & 31)) & 1u) && ((aw1b >> (v1b & 31)) & 1u);
        u32 slA = (u32)lane, slB = (u32)(64 + lane);
        bool confA = specA && ((((m0a & 0xFFFFFF00u) == gi) && ((m0a & 255u) < slA)) ||
                               (((m1a & 0xFFFFFF00u) == gi) && ((m1a & 255u) < slA)));
        bool confB = specB && ((((m0b & 0xFFFFFF00u) == gi) && ((m0b & 255u) < slB)) ||
                               (((m1b & 0xFFFFFF00u) == gi) && ((m1b & 255u) < slB)));
        u64 specLo = __ballot(specA), specHi = __ballot(specB);
        u64 confLo = __ballot(confA), confHi = __ballot(confB);
        u64 accLo = specLo & ~confLo, accHi = specHi & ~confHi;
        u64 rem = confLo; // resolve conflicted slots in slot order (lo then hi)
        while (rem) {
            int l = __ffsll((unsigned long long)rem) - 1; rem &= rem - 1;
            int bv0 = __shfl(v0a, l), bv1 = __shfl(v1a, l);
            bool kA = ((accLo >> lane) & 1ull) && (lane < l) && (v1a == bv0 || v1a == bv1);
            if (__ballot(kA) == 0ull) accLo |= 1ull << l;
        }
        rem = confHi;
        while (rem) {
            int l = __ffsll((unsigned long long)rem) - 1; rem &= rem - 1;
            int bv0 = __shfl(v0b, l), bv1 = __shfl(v1b, l);
            bool kA = ((accLo >> lane) & 1ull) && (v1a == bv0 || v1a == bv1); // lo slots all earlier
            bool kB = ((accHi >> lane) & 1ull) && (lane < l) && (v1b == bv0 || v1b == bv1);
            if ((__ballot(kA) | __ballot(kB)) == 0ull) accHi |= 1ull << l;
        }
        int cntLo = __popcll(accLo);
        int cnt = cntLo + __popcll(accHi);
        int remK = TGTK - nk;
        bool accA = (accLo >> lane) & 1ull;
        bool accB = (accHi >> lane) & 1ull;
        if (cnt > remK) { // keep first remK accepts in slot order (pre-trim ranks)
            int rA = __popcll(accLo & ((1ull << lane) - 1ull));
            if (accA && rA >= remK) accA = false;
            int rB = cntLo + __popcll(accHi & ((1ull << lane) - 1ull));
            if (accB && rB >= remK) accB = false;
            accLo = __ballot(accA); accHi = __ballot(accB);
            cntLo = __popcll(accLo);
            cnt = remK;
        }
        if (accA) {
            atomicAnd(&alive[v1a >> 5], ~(1u << (v1a & 31)));
            map[(size_t)b * Nv + v1a] = v0a;
            int r = __popcll(accLo & ((1ull << lane) - 1ull));
            int slot = nk + r;
            accList[((size_t)b * TGTK + slot) * 2] = v0a;
            accList[((size_t)b * TGTK + slot) * 2 + 1] = v1a;
        }
        if (accB) {
            atomicAnd(&alive[v1b >> 5], ~(1u << (v1b & 31)));
            map[(size_t)b * Nv + v1b] = v0b;
            int r = cntLo + __popcll(accHi & ((1ull << lane) - 1ull));
            int slot = nk + r;
            accList[((size_t)b * TGTK + slot) * 2] = v0b;
            accList[((size_t)b * TGTK + slot) * 2 + 1] = v1b;
        }
        nk += cnt;
        if (nk >= TGTK) break;
        pa = na; pb = nb;
    }
    if (lane == 0) accCnt[b] = (u32)nk;
    // ---------------- fused scan: ranks of alive vertices ----------------
    __syncthreads();
    __threadfence(); // commit this wave's map[] kill-writes before re-reading below
    u32 w0 = alive[lane * 4], w1 = alive[lane * 4 + 1];
    u32 w2 = alive[lane * 4 + 2], w3 = alive[lane * 4 + 3];
    u32 c0 = __popc(w0), c1 = __popc(w1), c2 = __popc(w2), c3 = __popc(w3);
    u32 lsum = c0 + c1 + c2 + c3;
    u32 incl = lsum;
#pragma unroll
    for (int d = 1; d < 64; d <<= 1) { u32 t = __shfl_up(incl, d); if (lane >= d) incl += t; }
    u32 base = incl - lsum; // exclusive prefix: rank base for vertex 128*lane
    int* posb = pos + (size_t)b * Nv;
    int* alb = alist + (size_t)b * Kv;
    __syncthreads(); // registry reads done; reuse mlane as pos[]
    u32 wv[4] = { w0, w1, w2, w3 };
    for (int q = 0; q < 4; ++q) {
        u32 w = wv[q];
        int vb = lane * 128 + q * 32;
        for (int bit = 0; bit < 32; ++bit) {
            int v = vb + bit;
            int p = -1;
            if ((w >> bit) & 1u) {
                if (base < Kv) { p = (int)base; alb[base] = v; }
                base++;
            }
            mlane[v] = (u32)p;
            posb[v] = p;
        }
    }
    __syncthreads();
    const int* mapb = map + (size_t)b * Nv;
    int* pmb = pm + (size_t)b * Nv;
    for (int v = lane; v < Nv; v += 64) pmb[v] = (int)mlane[(u32)mapb[v]];
}

// ---------------- features: copy surviving rows (+ zero outbits for k_merge) ----------------
__global__ void k_fcopy(const float* image, const int* alist, float* outF, u32* outbits) {
    int idx = blockIdx.x * 256 + threadIdx.x; // Bn*Kv*16
    if (idx >= Bn * Kv * 16) return;
    // zero outbits: Bn*Kv*128 = 2M words over 256K threads -> 8 words (32 B) each
    {
        uint4* ob = (uint4*)(outbits + (size_t)idx * 8);
        uint4 z = { 0, 0, 0, 0 };
        ob[0] = z; ob[1] = z;
    }
    int b = idx >> 16, r = idx & 65535;
    int x = r >> 4, f4 = r & 15;
    int src = alist[b * Kv + x];
    const float4* s = (const float4*)(image + ((size_t)(b * Nv + src)) * Fd) + f4;
    float4* d = (float4*)(outF + ((size_t)(b * Kv + x)) * Fd) + f4;
    *d = *s;
}

__global__ __launch_bounds__(64) void k_fscat(const float* image, const int* accList,
                                              const u32* accCnt, const int* pos, float* outF) {
    int b = blockIdx.x >> 12, e = blockIdx.x & 4095;
    if (e >= (int)accCnt[b]) return;
    int v0 = accList[((size_t)b * TGTK + e) * 2];
    int v1 = accList[((size_t)b * TGTK + e) * 2 + 1];
    int x = pos[(size_t)b * Nv + v0];
    if (x < 0) return;
    int f = threadIdx.x;
    atomicAdd(outF + ((size_t)(b * Kv + x)) * Fd + f,
              image[((size_t)(b * Nv + v1)) * Fd + f]);
}

// ---------------- adjacency: merge rows/cols into K-bit bitsets ----------------
__global__ __launch_bounds__(256) void k_merge(const u8* adj, const u32* flags,
                                               const int* pm, u32* outbits) {
    int bi = blockIdx.x; // Bn*Nv
    int b = bi >> 13, i = bi & (Nv - 1);
    int t = pm[(size_t)b * Nv + i];
    if (t < 0) return;
    __shared__ u32 bits[Kv / 32]; // 128 words
    int tid = threadIdx.x;
    if (tid < 128) bits[tid] = 0;
    __syncthreads();
    const int* pmb = pm + (size_t)b * Nv;
    u32 fw = flags[0];
    bool bytefmt = (fw & 1) && (fw & 8);
    auto put = [&](int col) {
        int c = pmb[col];
        if (c >= 0) atomicOr(&bits[c >> 5], 1u << (c & 31));
    };
    if (bytefmt) {
        const uint4* row = (const uint4*)(adj + ((size_t)b * Nv + i) * Nv);
#pragma unroll
        for (int it = 0; it < 2; ++it) {
            uint4 v = row[it * 256 + tid];
            if (v.x | v.y | v.z | v.w) {
                int cb = (it * 256 + tid) * 16;
                u32 wv[4] = { v.x, v.y, v.z, v.w };
                for (int q = 0; q < 4; ++q) {
                    u32 u = wv[q];
                    if (!u) continue;
#pragma unroll
                    for (int kk = 0; kk < 4; ++kk)
                        if ((u >> (8 * kk)) & 0xFFu) put(cb + q * 4 + kk);
                }
            }
        }
    } else {
        const uint4* row = (const uint4*)((const u32*)adj + ((size_t)b * Nv + i) * Nv);
        for (int it = 0; it < 8; ++it) {
            uint4 v = row[it * 256 + tid];
            int cb = (it * 256 + tid) * 4;
            if (v.x) put(cb);
            if (v.y) put(cb + 1);
            if (v.z) put(cb + 2);
            if (v.w) put(cb + 3);
        }
    }
    __syncthreads();
    if (tid < 128) {
        u32 bw = bits[tid];
        if (bw) atomicOr(&outbits[((size_t)b * Kv + t) * 128 + tid], bw);
    }
}

// ---------------- expand bitsets to float adjacency, zero diagonal ----------------
// one block per output row; row bitmap staged in LDS; 4 interleaved float4 stores/thread
__global__ __launch_bounds__(256) void k_expand(const u32* outbits, float* out) {
    int bi = blockIdx.x; // Bn*Kv
    int b = bi >> 12, x = bi & (Kv - 1);
    int tid = threadIdx.x;
    __shared__ u32 bits[128];
    if (tid < 128) bits[tid] = outbits[((size_t)b * Kv + x) * 128 + tid];
    __syncthreads();
    float* rowOut = out + ((size_t)(b * Kv + x)) * Kv;
#pragma unroll
    for (int q = 0; q < 4; ++q) {
        int c0 = q * 1024 + tid * 4;
        u32 w = bits[c0 >> 5];
        u32 nib = (w >> (c0 & 31)) & 0xFu;
        float4 f;
        f.x = (nib & 1) ? 1.f : 0.f;
        f.y = (nib & 2) ? 1.f : 0.f;
        f.z = (nib & 4) ? 1.f : 0.f;
        f.w = (nib & 8) ? 1.f : 0.f;
        if (x >= c0 && x < c0 + 4) ((float*)&f)[x - c0] = 0.f;
        *((float4*)(rowOut + c0)) = f;
    }
}

extern "C" void kernel_launch(void* const* d_in, const int* in_sizes, int n_in,
                              void* d_out, int out_size, void* d_ws, size_t ws_size,
                              hipStream_t stream) {
    const u8* adj = (const u8*)d_in[0];
    const float* image = (const float*)d_in[1];
    const float* vs = (const float*)d_in[2];
    const int* edges = (const int*)d_in[3];
    char* ws = (char*)d_ws;
    u32* flags = (u32*)(ws + WS_FLAGS);
    u32* accCnt = (u32*)(ws + WS_ACCCNT);
    u32* outbits = (u32*)(ws + WS_OUTBITS);
    u64* keys = (u64*)(ws + WS_KEYS);
    float* sq = (float*)(ws + WS_SQ);
    u8* bnd = (u8*)(ws + WS_BND);
    int* map = (int*)(ws + WS_MAP);
    int* pos = (int*)(ws + WS_POS);
    int* pm = (int*)(ws + WS_PM);
    int* alist = (int*)(ws + WS_ALIST);
    int* accList = (int*)(ws + WS_ACC);
    u32* pack = (u32*)(ws + WS_PACK);
    u32* spack = (u32*)(ws + WS_SPACK);
    float* outA = (float*)d_out;
    float* outF = outA + (size_t)Bn * Kv * Kv;

    hipMemsetAsync(d_ws, 0, WS_ZERO_BYTES, stream); // flags only; outbits zeroed in k_fcopy
    k_vertex<<<Bn * Nv / 256, 256, 0, stream>>>(image, vs, sq, bnd, map, adj, flags);
    k_edge<<<Bn * Ed / 256, 256, 0, stream>>>(edges, sq, bnd, keys, pack);
    // bitonic sort: local chunks, vertical register merges, LDS finishes
    k_sortA<<<Bn * 8, 1024, 0, stream>>>(keys);
    k_sortV<<<Bn * 8, 1024, 0, stream>>>(keys, 16384);
    k_sortC<<<Bn * 8, 1024, 0, stream>>>(keys, 16384, pack, spack, 0);
    k_sortV<<<Bn * 8, 1024, 0, stream>>>(keys, 32768);
    k_sortC<<<Bn * 8, 1024, 0, stream>>>(keys, 32768, pack, spack, 0);
    k_sortV<<<Bn * 8, 1024, 0, stream>>>(keys, 65536);
    k_sortC<<<Bn * 8, 1024, 0, stream>>>(keys, 65536, pack, spack, 1);
    k_greedy<<<Bn, 64, 0, stream>>>(spack, map, accList, accCnt, pos, pm, alist);
    k_fcopy<<<Bn * Kv * 16 / 256, 256, 0, stream>>>(image, alist, outF, outbits);
    k_fscat<<<Bn * TGTK, 64, 0, stream>>>(image, accList, accCnt, pos, outF);
    k_merge<<<Bn * Nv, 256, 0, stream>>>(adj, flags, pm, outbits);
    k_expand<<<Bn * Kv, 256, 0, stream>>>(outbits, outA);
}